// Round 9
// baseline (336.757 us; speedup 1.0000x reference)
//
#include <hip/hip_runtime.h>

#define B_   2
#define S_   2048
#define H_   2048
#define NH_  16
#define HS_  128
#define NORM_ 0.08838834764831845f          // 128^-0.5
#define L2B16 0.8304820237218407f           // log2(10000)/16

typedef unsigned short bf16_t;
typedef __bf16 bf16x8 __attribute__((ext_vector_type(8)));
typedef float  f32x4  __attribute__((ext_vector_type(4)));

__device__ __forceinline__ float b2f(bf16_t u) {
    return __uint_as_float(((unsigned int)u) << 16);
}
__device__ __forceinline__ bf16_t f2b(float f) {
    unsigned int x = __float_as_uint(f);
    x += 0x7fffu + ((x >> 16) & 1u);        // round-to-nearest-even
    return (bf16_t)(x >> 16);
}

__device__ __forceinline__ void async16(bf16_t* lds, const bf16_t* g) {
    __builtin_amdgcn_global_load_lds(
        (const __attribute__((address_space(1))) void*)g,
        (__attribute__((address_space(3))) void*)lds, 16, 0, 0);
}

__device__ __forceinline__ f32x4 mfma16(bf16x8 a, bf16x8 b, f32x4 c) {
    return __builtin_amdgcn_mfma_f32_16x16x32_bf16(a, b, c, 0, 0, 0);
}

#define BAR()        asm volatile("s_barrier" ::: "memory")
#define WAIT_VM0()   asm volatile("s_waitcnt vmcnt(0)" ::: "memory")
#define WAIT_VM8()   asm volatile("s_waitcnt vmcnt(8)" ::: "memory")

// ---------------- f32 -> bf16 convert (8 elems/thread) ----------------
__global__ __launch_bounds__(256) void cvt_bf16(const float* __restrict__ in,
                                                bf16_t* __restrict__ out) {
    const size_t i = (size_t)blockIdx.x * 256 + threadIdx.x;
    const float4* p = (const float4*)in + i * 2;
    float4 a = p[0], b = p[1];
    bf16_t o[8] = { f2b(a.x), f2b(a.y), f2b(a.z), f2b(a.w),
                    f2b(b.x), f2b(b.y), f2b(b.z), f2b(b.w) };
    *((bf16x8*)out + i) = *(const bf16x8*)o;
}

// ---------------- W (KxN f32) -> W^T (NxK bf16), 32x32 tiles ----------------
__global__ __launch_bounds__(256) void transpose_cvt(const float* __restrict__ W,
                                                     bf16_t* __restrict__ WT,
                                                     int K, int N) {
    __shared__ float tile[32][33];
    const int tx = threadIdx.x & 31, ty = threadIdx.x >> 5;
    const int n0 = blockIdx.x * 32, k0 = blockIdx.y * 32;
#pragma unroll
    for (int i = 0; i < 4; i++)
        tile[ty + i * 8][tx] = W[(size_t)(k0 + ty + i * 8) * N + n0 + tx];
    __syncthreads();
#pragma unroll
    for (int i = 0; i < 4; i++)
        WT[(size_t)(n0 + ty + i * 8) * K + k0 + tx] = f2b(tile[tx][ty + i * 8]);
}

// ---------------- shared staging helper (512-thread blocks) ----------------
__device__ __forceinline__ void st512(bf16_t* lds, const bf16_t* g,
                                      int K, int part, int tid) {
    const int idx = part * 512 + tid;
    const int row = idx >> 3, slot = idx & 7;
    async16(lds + idx * 8, g + (size_t)row * K + ((slot ^ (row & 7)) << 3));
}

#define LDAQ(dst, ab, q) do {                                                  \
    _Pragma("unroll")                                                          \
    for (int m = 0; m < 2; m++)                                                \
        _Pragma("unroll")                                                      \
        for (int ks = 0; ks < 2; ks++) {                                       \
            const int r = wm * 128 + (q) * 32 + m * 16 + lr;                   \
            dst[m][ks] = *(const bf16x8*)                                      \
                &(ab)[r * 64 + (((ks * 4 + ls) ^ (r & 7)) << 3)];              \
        }                                                                      \
} while (0)

// ---------------- 256x192 single-barrier GEMM (QKV) ------------------------
#define LDB3(bb) do {                                                          \
    _Pragma("unroll")                                                          \
    for (int n = 0; n < 3; n++)                                                \
        _Pragma("unroll")                                                      \
        for (int ks = 0; ks < 2; ks++) {                                       \
            const int r = wn * 48 + n * 16 + lr;                               \
            bfr[n][ks] = *(const bf16x8*)                                      \
                &(bb)[r * 64 + (((ks * 4 + ls) ^ (r & 7)) << 3)];              \
        }                                                                      \
} while (0)

#define MMA3(q, src) do {                                                      \
    __builtin_amdgcn_s_setprio(1);                                             \
    _Pragma("unroll")                                                          \
    for (int ks = 0; ks < 2; ks++)                                             \
        _Pragma("unroll")                                                      \
        for (int n = 0; n < 3; n++)                                            \
            _Pragma("unroll")                                                  \
            for (int m = 0; m < 2; m++)                                        \
                acc[(q) * 2 + m][n] =                                          \
                    mfma16(src[m][ks], bfr[n][ks], acc[(q) * 2 + m][n]);       \
    __builtin_amdgcn_s_setprio(0);                                             \
} while (0)

__global__ __launch_bounds__(512, 2) void gemm_qkv(const bf16_t* __restrict__ A,
                                                   const bf16_t* __restrict__ BT,
                                                   const float* __restrict__ bias,
                                                   bf16_t* __restrict__ C,
                                                   int M, int N, int K) {
    __shared__ __align__(16) bf16_t As[2][256 * 64];
    __shared__ __align__(16) bf16_t Bs[2][192 * 64];

    const int nwg = (int)(gridDim.x * gridDim.y);
    const int id  = (int)(blockIdx.y * gridDim.x + blockIdx.x);
    const int wg  = (id & 7) * (nwg >> 3) + (id >> 3);      // XCD-bijective
    const int bx  = wg % (int)gridDim.x, by = wg / (int)gridDim.x;

    const int tid = threadIdx.x;
    const int wid = tid >> 6, lane = tid & 63;
    const int lr = lane & 15, ls = lane >> 4;
    const int wm = wid >> 2, wn = wid & 3;
    const size_t m0 = (size_t)by * 256, n0 = (size_t)bx * 192;

    const bf16_t* Ab = A + m0 * K;
    const bf16_t* Bb = BT + n0 * K;

    f32x4 acc[8][3];
#pragma unroll
    for (int m = 0; m < 8; m++)
#pragma unroll
        for (int n = 0; n < 3; n++) acc[m][n] = (f32x4){0.f, 0.f, 0.f, 0.f};
    bf16x8 bfr[3][2];
    bf16x8 afP[2][2], afQ[2][2];

#pragma unroll
    for (int p = 0; p < 4; p++) st512(As[0], Ab, K, p, tid);
#pragma unroll
    for (int p = 0; p < 3; p++) st512(Bs[0], Bb, K, p, tid);
    WAIT_VM0();
    BAR();

    const int nt = K >> 6;
#pragma unroll 1
    for (int i = 0; i < nt; ++i) {
        const int c = i & 1;
        const bf16_t* Ac = As[c];
        const bf16_t* Bc = Bs[c];
        if (i + 1 < nt) {
            const size_t ko = (size_t)(i + 1) * 64;
            bf16_t* Ad = As[c ^ 1];
            bf16_t* Bd = Bs[c ^ 1];
#pragma unroll
            for (int p = 0; p < 4; p++) st512(Ad, Ab + ko, K, p, tid);
#pragma unroll
            for (int p = 0; p < 3; p++) st512(Bd, Bb + ko, K, p, tid);
        }
        __builtin_amdgcn_sched_barrier(0);
        LDAQ(afP, Ac, 0);
        LDB3(Bc);
        LDAQ(afQ, Ac, 1);
        MMA3(0, afP);
        LDAQ(afP, Ac, 2);
        MMA3(1, afQ);
        LDAQ(afQ, Ac, 3);
        MMA3(2, afP);
        MMA3(3, afQ);
        WAIT_VM0();
        BAR();
    }

    float bv[3];
#pragma unroll
    for (int n = 0; n < 3; n++) bv[n] = bias[n0 + wn * 48 + n * 16 + lr];
#pragma unroll
    for (int mm = 0; mm < 8; mm++)
#pragma unroll
        for (int n = 0; n < 3; n++)
#pragma unroll
            for (int j = 0; j < 4; j++) {
                const size_t row = m0 + wm * 128 + mm * 16 + ls * 4 + j;
                const size_t col = n0 + wn * 48 + n * 16 + lr;
                C[row * N + col] = f2b(acc[mm][n][j] + bv[n]);
            }
}

// ---------------- 256x128 single-barrier GEMM (dense, 1 round) --------------
#define LDB2(bb) do {                                                          \
    _Pragma("unroll")                                                          \
    for (int n = 0; n < 2; n++)                                                \
        _Pragma("unroll")                                                      \
        for (int ks = 0; ks < 2; ks++) {                                       \
            const int r = wn * 32 + n * 16 + lr;                               \
            bfr[n][ks] = *(const bf16x8*)                                      \
                &(bb)[r * 64 + (((ks * 4 + ls) ^ (r & 7)) << 3)];              \
        }                                                                      \
} while (0)

#define MMA2(q, src) do {                                                      \
    __builtin_amdgcn_s_setprio(1);                                             \
    _Pragma("unroll")                                                          \
    for (int ks = 0; ks < 2; ks++)                                             \
        _Pragma("unroll")                                                      \
        for (int n = 0; n < 2; n++)                                            \
            _Pragma("unroll")                                                  \
            for (int m = 0; m < 2; m++)                                        \
                acc[(q) * 2 + m][n] =                                          \
                    mfma16(src[m][ks], bfr[n][ks], acc[(q) * 2 + m][n]);       \
    __builtin_amdgcn_s_setprio(0);                                             \
} while (0)

__global__ __launch_bounds__(512, 2) void gemm_dense(const bf16_t* __restrict__ A,
                                                     const bf16_t* __restrict__ BT,
                                                     const float* __restrict__ bias,
                                                     float* __restrict__ C,
                                                     int M, int N, int K) {
    __shared__ __align__(16) bf16_t As[2][256 * 64];
    __shared__ __align__(16) bf16_t Bs[2][128 * 64];

    const int nwg = (int)(gridDim.x * gridDim.y);
    const int id  = (int)(blockIdx.y * gridDim.x + blockIdx.x);
    const int wg  = (id & 7) * (nwg >> 3) + (id >> 3);
    const int bx  = wg % (int)gridDim.x, by = wg / (int)gridDim.x;

    const int tid = threadIdx.x;
    const int wid = tid >> 6, lane = tid & 63;
    const int lr = lane & 15, ls = lane >> 4;
    const int wm = wid >> 2, wn = wid & 3;
    const size_t m0 = (size_t)by * 256, n0 = (size_t)bx * 128;

    const bf16_t* Ab = A + m0 * K;
    const bf16_t* Bb = BT + n0 * K;

    f32x4 acc[8][2];
#pragma unroll
    for (int m = 0; m < 8; m++)
#pragma unroll
        for (int n = 0; n < 2; n++) acc[m][n] = (f32x4){0.f, 0.f, 0.f, 0.f};
    bf16x8 bfr[2][2];
    bf16x8 afP[2][2], afQ[2][2];

#pragma unroll
    for (int p = 0; p < 4; p++) st512(As[0], Ab, K, p, tid);
#pragma unroll
    for (int p = 0; p < 2; p++) st512(Bs[0], Bb, K, p, tid);
    WAIT_VM0();
    BAR();

    const int nt = K >> 6;
#pragma unroll 1
    for (int i = 0; i < nt; ++i) {
        const int c = i & 1;
        const bf16_t* Ac = As[c];
        const bf16_t* Bc = Bs[c];
        if (i + 1 < nt) {
            const size_t ko = (size_t)(i + 1) * 64;
            bf16_t* Ad = As[c ^ 1];
            bf16_t* Bd = Bs[c ^ 1];
#pragma unroll
            for (int p = 0; p < 4; p++) st512(Ad, Ab + ko, K, p, tid);
#pragma unroll
            for (int p = 0; p < 2; p++) st512(Bd, Bb + ko, K, p, tid);
        }
        __builtin_amdgcn_sched_barrier(0);
        LDAQ(afP, Ac, 0);
        LDB2(Bc);
        LDAQ(afQ, Ac, 1);
        MMA2(0, afP);
        LDAQ(afP, Ac, 2);
        MMA2(1, afQ);
        LDAQ(afQ, Ac, 3);
        MMA2(2, afP);
        MMA2(3, afQ);
        WAIT_VM0();
        BAR();
    }

    float bv[2];
#pragma unroll
    for (int n = 0; n < 2; n++) bv[n] = bias[n0 + wn * 32 + n * 16 + lr];
#pragma unroll
    for (int mm = 0; mm < 8; mm++)
#pragma unroll
        for (int n = 0; n < 2; n++)
#pragma unroll
            for (int j = 0; j < 4; j++) {
                const size_t row = m0 + wm * 128 + mm * 16 + ls * 4 + j;
                const size_t col = n0 + wn * 32 + n * 16 + lr;
                C[row * N + col] = acc[mm][n][j] + bv[n];
            }
}

// ---------------- RoPE on Q,K only (pow-2 indexing) ----------------
__global__ __launch_bounds__(256) void rope_qk(const bf16_t* __restrict__ qkv,
                                               const int* __restrict__ pos_ids,
                                               bf16_t* __restrict__ Qo,
                                               bf16_t* __restrict__ Ko) {
    const size_t gid = (size_t)blockIdx.x * 256 + threadIdx.x;
    const int d8 = (int)(gid & 15);
    const size_t t1 = gid >> 4;
    const int which = (int)(t1 & 1);
    const size_t t2 = t1 >> 1;
    const int nh = (int)(t2 & 15);
    const size_t bs = t2 >> 4;                  // b*S + s
    const int s = (int)(bs & (S_ - 1));
    const int b = (int)(bs >> 11);

    const bf16_t* src = qkv + bs * (3 * H_) + nh * 384 + which * 128 + d8 * 8;
    bf16x8 xv = *(const bf16x8*)src;
    const bf16_t* xu = (const bf16_t*)&xv;

    float xf[8];
#pragma unroll
    for (int i = 0; i < 8; i++) xf[i] = b2f(xu[i]);
    const int d0 = d8 * 8;
    if (d0 < 32) {
        const float pos = (float)pos_ids[bs];
        bf16x8 yv = *(const bf16x8*)(src + ((d0 < 16) ? 16 : -16));
        const bf16_t* yu = (const bf16_t*)&yv;
#pragma unroll
        for (int i = 0; i < 8; i++) {
            const int d = d0 + i;
            const float th = pos * exp2f(-(float)(d & 15) * L2B16);
            const float c = cosf(th), sn = sinf(th);
            const float rot = (d < 16) ? -b2f(yu[i]) : b2f(yu[i]);
            xf[i] = xf[i] * c + rot * sn;
        }
    }
    bf16_t ou[8];
#pragma unroll
    for (int i = 0; i < 8; i++) ou[i] = f2b(xf[i]);
    bf16_t* dst = ((which == 0) ? Qo : Ko) + ((size_t)(b * NH_ + nh) * S_ + s) * HS_ + d0;
    *(bf16x8*)dst = *(const bf16x8*)ou;
}

// ---------------- V transpose: (b,s,h,d) -> (bh, d, s), LDS-tiled ----------
__global__ __launch_bounds__(256) void vxpose(const bf16_t* __restrict__ qkv,
                                              bf16_t* __restrict__ Vt) {
    __shared__ bf16_t t[128][130];
    const int bh = (int)blockIdx.x >> 4;
    const int s0 = ((int)blockIdx.x & 15) << 7;
    const int b = bh >> 4, h = bh & 15;
    const int tid = threadIdx.x;

    const int dc = tid & 15, sl = tid >> 4;
    const bf16_t* src = qkv + ((size_t)b * S_ + s0) * (3 * H_) + h * 384 + 256 + dc * 8;
#pragma unroll
    for (int c = 0; c < 8; c++) {
        const int s = sl + c * 16;
        bf16x8 v = *(const bf16x8*)(src + (size_t)s * (3 * H_));
        *(bf16x8*)&t[s][dc * 8] = v;
    }
    __syncthreads();
    const int sc = tid & 15, dl = tid >> 4;
    bf16_t* dst = Vt + ((size_t)bh * HS_) * S_ + s0 + sc * 8;
#pragma unroll
    for (int c = 0; c < 8; c++) {
        const int d = dl + c * 16;
        bf16_t o[8];
#pragma unroll
        for (int i = 0; i < 8; i++) o[i] = t[sc * 8 + i][d];
        *(bf16x8*)(dst + (size_t)d * S_) = *(const bf16x8*)o;
    }
}

// ---------------- causal flash attention v3: QBLK=32/wave -------------------
// Block = 128 q-rows (4 waves x 32), KVBLK=64 dbuf. kf/vf fragments shared
// across the two u-subtiles (2 MFMAs per LDS read). Ps region (16 rows/wave)
// reused u=0 then u=1 with pf preloaded to registers between (in-order DS).
// Grid (32 bh, 16 tiles) heavy-first; bh == XCD gives 4 bh per XCD L2.
__device__ __forceinline__ void attn_stage(bf16_t* Kd, bf16_t* Vd,
                                           const bf16_t* Kg, const bf16_t* Vg,
                                           int kv0, int wid, int lane) {
#pragma unroll
    for (int jj = 0; jj < 4; jj++) {
        const int c = (wid << 2) + jj;
        const int rk = (c << 2) + (lane >> 4);        // K row 0..63
        async16(Kd + c * 512,
                Kg + (size_t)(kv0 + rk) * HS_ + (((lane & 15) ^ (rk & 7)) << 3));
        const int rv = (c << 3) + (lane >> 3);        // V^T row 0..127
        async16(Vd + c * 512,
                Vg + (size_t)rv * S_ + kv0 + (((lane & 7) ^ (rv & 7)) << 3));
    }
}

__global__ __launch_bounds__(256) void attn_fwd(const bf16_t* __restrict__ Q,
                                                const bf16_t* __restrict__ Kv,
                                                const bf16_t* __restrict__ Vt,
                                                const float* __restrict__ amask,
                                                bf16_t* __restrict__ ctx) {
    __shared__ __align__(16) bf16_t Ks[2][64 * 128];
    __shared__ __align__(16) bf16_t Vs[2][128 * 64];
    __shared__ __align__(16) bf16_t Ps[4][16 * 72];

    const int bh = (int)blockIdx.x;               // XCD = bh & 7
    const int qt = 15 - (int)blockIdx.y;          // heavy tiles first
    const int q0 = qt << 7;                       // 128-row q tile
    const int b = bh >> 4, h = bh & 15;
    const int tid = threadIdx.x, wid = tid >> 6, lane = tid & 63;
    const int lr = lane & 15, ls = lane >> 4;
    const float* am = amask + (size_t)b * S_;
    const bf16_t* Kg = Kv + (size_t)bh * S_ * HS_;
    const bf16_t* Vg = Vt + (size_t)bh * HS_ * S_;

    const int qb = q0 + wid * 32;                 // wave's 32-row q base
    bf16x8 qf[2][4];
#pragma unroll
    for (int u = 0; u < 2; u++) {
        const bf16_t* qp = Q + ((size_t)bh * S_ + qb + u * 16 + lr) * HS_;
#pragma unroll
        for (int dk = 0; dk < 4; dk++) qf[u][dk] = *(const bf16x8*)(qp + dk * 32 + ls * 8);
    }

    float mrun[2] = { -3.0e38f, -3.0e38f }, lrun[2] = { 0.f, 0.f };
    f32x4 oacc[2][8];
#pragma unroll
    for (int u = 0; u < 2; u++)
#pragma unroll
        for (int dt = 0; dt < 8; dt++) oacc[u][dt] = (f32x4){0.f, 0.f, 0.f, 0.f};

    attn_stage(Ks[0], Vs[0], Kg, Vg, 0, wid, lane);
    const int nsteps = 2 * qt + 2;
#pragma unroll 1
    for (int step = 0; step < nsteps; ++step) {
        const int cur = step & 1;
        const int kv0 = step << 6;
        if (step + 1 < nsteps) {
            attn_stage(Ks[cur ^ 1], Vs[cur ^ 1], Kg, Vg, kv0 + 64, wid, lane);
            WAIT_VM8();
        } else {
            WAIT_VM0();
        }
        BAR();

        // QK^T, kf shared across u
        f32x4 sacc[2][4];
#pragma unroll
        for (int u = 0; u < 2; u++)
#pragma unroll
            for (int tt = 0; tt < 4; tt++) sacc[u][tt] = (f32x4){0.f, 0.f, 0.f, 0.f};
#pragma unroll
        for (int tt = 0; tt < 4; tt++)
#pragma unroll
            for (int dk = 0; dk < 4; dk++) {
                const int row = tt * 16 + lr;
                bf16x8 kf = *(const bf16x8*)
                    &Ks[cur][row * 128 + (((dk * 4 + ls) ^ (row & 7)) << 3)];
                sacc[0][tt] = mfma16(kf, qf[0][dk], sacc[0][tt]);
                sacc[1][tt] = mfma16(kf, qf[1][dk], sacc[1][tt]);
            }

        const bool diag = (step >= 2 * qt);
        bf16x8 pfr[2][2];
#pragma unroll
        for (int u = 0; u < 2; u++) {
            const int qrow = qb + u * 16 + lr;
            float sv[4][4];
            float rmax = -3.0e38f;
#pragma unroll
            for (int tt = 0; tt < 4; tt++) {
                const float4 amv = *(const float4*)&am[kv0 + tt * 16 + ls * 4];
                const float amj[4] = { amv.x, amv.y, amv.z, amv.w };
#pragma unroll
                for (int j = 0; j < 4; j++) {
                    const int kvp = kv0 + tt * 16 + ls * 4 + j;
                    float v = sacc[u][tt][j] * NORM_ + amj[j];
                    if (diag && kvp > qrow) v = -3.0e38f;
                    sv[tt][j] = v;
                    rmax = fmaxf(rmax, v);
                }
            }
            rmax = fmaxf(rmax, __shfl_xor(rmax, 16));
            rmax = fmaxf(rmax, __shfl_xor(rmax, 32));

            if (!__all((int)(rmax <= mrun[u]))) {
                const float mnew = fmaxf(mrun[u], rmax);
                const float sc = __expf(mrun[u] - mnew);
                lrun[u] *= sc;
                mrun[u] = mnew;
                float scb[4];
#pragma unroll
                for (int j = 0; j < 4; j++) scb[j] = __shfl(sc, ls * 4 + j);
#pragma unroll
                for (int dt = 0; dt < 8; dt++)
#pragma unroll
                    for (int j = 0; j < 4; j++) oacc[u][dt][j] *= scb[j];
            }

            float psum = 0.f;
#pragma unroll
            for (int tt = 0; tt < 4; tt++) {
                const float p0 = __expf(sv[tt][0] - mrun[u]);
                const float p1 = __expf(sv[tt][1] - mrun[u]);
                const float p2 = __expf(sv[tt][2] - mrun[u]);
                const float p3 = __expf(sv[tt][3] - mrun[u]);
                psum += (p0 + p1) + (p2 + p3);
                const unsigned pk0 = (unsigned)f2b(p0) | ((unsigned)f2b(p1) << 16);
                const unsigned pk1 = (unsigned)f2b(p2) | ((unsigned)f2b(p3) << 16);
                *(unsigned*)&Ps[wid][lr * 72 + tt * 16 + ls * 4]     = pk0;
                *(unsigned*)&Ps[wid][lr * 72 + tt * 16 + ls * 4 + 2] = pk1;
            }
            psum += __shfl_xor(psum, 16);
            psum += __shfl_xor(psum, 32);
            lrun[u] += psum;

            // preload this u's P-frags to registers, freeing Ps for u=1
            pfr[u][0] = *(const bf16x8*)&Ps[wid][lr * 72 + ls * 8];
            pfr[u][1] = *(const bf16x8*)&Ps[wid][lr * 72 + 32 + ls * 8];
        }

        // PV, vf shared across u
#pragma unroll
        for (int dt = 0; dt < 8; dt++)
#pragma unroll
            for (int hh = 0; hh < 2; hh++) {
                const int vrow = dt * 16 + lr;
                bf16x8 vf = *(const bf16x8*)
                    &Vs[cur][vrow * 64 + (((hh * 4 + ls) ^ (vrow & 7)) << 3)];
                oacc[0][dt] = mfma16(pfr[0][hh], vf, oacc[0][dt]);
                oacc[1][dt] = mfma16(pfr[1][hh], vf, oacc[1][dt]);
            }
        BAR();
    }

#pragma unroll
    for (int u = 0; u < 2; u++) {
        const float inv = 1.0f / lrun[u];
        float invj[4];
#pragma unroll
        for (int j = 0; j < 4; j++) invj[j] = __shfl(inv, ls * 4 + j);
#pragma unroll
        for (int j = 0; j < 4; j++) {
            bf16_t* dst = ctx + ((size_t)b * S_ + qb + u * 16 + ls * 4 + j) * H_ + h * HS_;
#pragma unroll
            for (int dt = 0; dt < 8; dt++) dst[dt * 16 + lr] = f2b(oacc[u][dt][j] * invj[j]);
        }
    }
}

extern "C" void kernel_launch(void* const* d_in, const int* in_sizes, int n_in,
                              void* d_out, int out_size, void* d_ws, size_t ws_size,
                              hipStream_t stream) {
    const float* hs   = (const float*)d_in[0];
    const float* am   = (const float*)d_in[1];
    const int*   pos  = (const int*)d_in[2];
    const float* Wqkv = (const float*)d_in[3];
    const float* bqkv = (const float*)d_in[4];
    const float* Wd   = (const float*)d_in[5];
    const float* bd   = (const float*)d_in[6];
    float* out = (float*)d_out;
    char*  ws  = (char*)d_ws;

    const size_t MB = 1024 * 1024;
    bf16_t* X    = (bf16_t*)(ws);              // 16 MB (reused as ctx)
    bf16_t* WqT  = (bf16_t*)(ws + 16 * MB);    // 24 MB
    bf16_t* WdT  = (bf16_t*)(ws + 40 * MB);    // 8 MB
    bf16_t* QKVb = (bf16_t*)(ws + 48 * MB);    // 48 MB
    bf16_t* Qb   = (bf16_t*)(ws + 96 * MB);    // 16 MB
    bf16_t* Kb   = (bf16_t*)(ws + 112 * MB);   // 16 MB
    bf16_t* Vtb  = (bf16_t*)(ws + 128 * MB);   // 16 MB
    bf16_t* ctx  = X;

    cvt_bf16<<<4096, 256, 0, stream>>>(hs, X);
    transpose_cvt<<<dim3(6144 / 32, 2048 / 32), 256, 0, stream>>>(Wqkv, WqT, 2048, 6144);
    transpose_cvt<<<dim3(2048 / 32, 2048 / 32), 256, 0, stream>>>(Wd, WdT, 2048, 2048);
    gemm_qkv<<<dim3(32, 16), 512, 0, stream>>>(X, WqT, bqkv, QKVb, 4096, 6144, 2048);
    rope_qk<<<8192, 256, 0, stream>>>(QKVb, pos, Qb, Kb);
    vxpose<<<512, 256, 0, stream>>>(QKVb, Vtb);
    attn_fwd<<<dim3(32, 16), 256, 0, stream>>>(Qb, Kb, Vtb, am, ctx);
    gemm_dense<<<dim3(16, 16), 512, 0, stream>>>(ctx, WdT, bd, out, 4096, 2048, 2048);
}

// Round 10
// 336.605 us; speedup vs baseline: 1.0005x; 1.0005x over previous
//
#include <hip/hip_runtime.h>

#define B_   2
#define S_   2048
#define H_   2048
#define NH_  16
#define HS_  128
#define NORM_ 0.08838834764831845f          // 128^-0.5
#define L2B16 0.8304820237218407f           // log2(10000)/16

typedef unsigned short bf16_t;
typedef __bf16 bf16x8 __attribute__((ext_vector_type(8)));
typedef float  f32x4  __attribute__((ext_vector_type(4)));

__device__ __forceinline__ float b2f(bf16_t u) {
    return __uint_as_float(((unsigned int)u) << 16);
}
__device__ __forceinline__ bf16_t f2b(float f) {
    unsigned int x = __float_as_uint(f);
    x += 0x7fffu + ((x >> 16) & 1u);        // round-to-nearest-even
    return (bf16_t)(x >> 16);
}

__device__ __forceinline__ void async16(bf16_t* lds, const bf16_t* g) {
    __builtin_amdgcn_global_load_lds(
        (const __attribute__((address_space(1))) void*)g,
        (__attribute__((address_space(3))) void*)lds, 16, 0, 0);
}

__device__ __forceinline__ f32x4 mfma16(bf16x8 a, bf16x8 b, f32x4 c) {
    return __builtin_amdgcn_mfma_f32_16x16x32_bf16(a, b, c, 0, 0, 0);
}

#define BAR()        asm volatile("s_barrier" ::: "memory")
#define WAIT_VM0()   asm volatile("s_waitcnt vmcnt(0)" ::: "memory")
#define WAIT_VM8()   asm volatile("s_waitcnt vmcnt(8)" ::: "memory")

// ---------------- f32 -> bf16 convert (8 elems/thread) ----------------
__global__ __launch_bounds__(256) void cvt_bf16(const float* __restrict__ in,
                                                bf16_t* __restrict__ out) {
    const size_t i = (size_t)blockIdx.x * 256 + threadIdx.x;
    const float4* p = (const float4*)in + i * 2;
    float4 a = p[0], b = p[1];
    bf16_t o[8] = { f2b(a.x), f2b(a.y), f2b(a.z), f2b(a.w),
                    f2b(b.x), f2b(b.y), f2b(b.z), f2b(b.w) };
    *((bf16x8*)out + i) = *(const bf16x8*)o;
}

// ---------------- W (KxN f32) -> W^T (NxK bf16), 32x32 tiles ----------------
__global__ __launch_bounds__(256) void transpose_cvt(const float* __restrict__ W,
                                                     bf16_t* __restrict__ WT,
                                                     int K, int N) {
    __shared__ float tile[32][33];
    const int tx = threadIdx.x & 31, ty = threadIdx.x >> 5;
    const int n0 = blockIdx.x * 32, k0 = blockIdx.y * 32;
#pragma unroll
    for (int i = 0; i < 4; i++)
        tile[ty + i * 8][tx] = W[(size_t)(k0 + ty + i * 8) * N + n0 + tx];
    __syncthreads();
#pragma unroll
    for (int i = 0; i < 4; i++)
        WT[(size_t)(n0 + ty + i * 8) * K + k0 + tx] = f2b(tile[tx][ty + i * 8]);
}

// ---------------- shared staging helper (512-thread blocks) ----------------
__device__ __forceinline__ void st512(bf16_t* lds, const bf16_t* g,
                                      int K, int part, int tid) {
    const int idx = part * 512 + tid;
    const int row = idx >> 3, slot = idx & 7;
    async16(lds + idx * 8, g + (size_t)row * K + ((slot ^ (row & 7)) << 3));
}

#define LDAQ(dst, ab, q) do {                                                  \
    _Pragma("unroll")                                                          \
    for (int m = 0; m < 2; m++)                                                \
        _Pragma("unroll")                                                      \
        for (int ks = 0; ks < 2; ks++) {                                       \
            const int r = wm * 128 + (q) * 32 + m * 16 + lr;                   \
            dst[m][ks] = *(const bf16x8*)                                      \
                &(ab)[r * 64 + (((ks * 4 + ls) ^ (r & 7)) << 3)];              \
        }                                                                      \
} while (0)

// ---------------- 256x192 single-barrier GEMM (QKV) ------------------------
#define LDB3(bb) do {                                                          \
    _Pragma("unroll")                                                          \
    for (int n = 0; n < 3; n++)                                                \
        _Pragma("unroll")                                                      \
        for (int ks = 0; ks < 2; ks++) {                                       \
            const int r = wn * 48 + n * 16 + lr;                               \
            bfr[n][ks] = *(const bf16x8*)                                      \
                &(bb)[r * 64 + (((ks * 4 + ls) ^ (r & 7)) << 3)];              \
        }                                                                      \
} while (0)

#define MMA3(q, src) do {                                                      \
    __builtin_amdgcn_s_setprio(1);                                             \
    _Pragma("unroll")                                                          \
    for (int ks = 0; ks < 2; ks++)                                             \
        _Pragma("unroll")                                                      \
        for (int n = 0; n < 3; n++)                                            \
            _Pragma("unroll")                                                  \
            for (int m = 0; m < 2; m++)                                        \
                acc[(q) * 2 + m][n] =                                          \
                    mfma16(src[m][ks], bfr[n][ks], acc[(q) * 2 + m][n]);       \
    __builtin_amdgcn_s_setprio(0);                                             \
} while (0)

__global__ __launch_bounds__(512, 2) void gemm_qkv(const bf16_t* __restrict__ A,
                                                   const bf16_t* __restrict__ BT,
                                                   const float* __restrict__ bias,
                                                   bf16_t* __restrict__ C,
                                                   int M, int N, int K) {
    __shared__ __align__(16) bf16_t As[2][256 * 64];
    __shared__ __align__(16) bf16_t Bs[2][192 * 64];

    const int nwg = (int)(gridDim.x * gridDim.y);
    const int id  = (int)(blockIdx.y * gridDim.x + blockIdx.x);
    const int wg  = (id & 7) * (nwg >> 3) + (id >> 3);      // XCD-bijective
    const int bx  = wg % (int)gridDim.x, by = wg / (int)gridDim.x;

    const int tid = threadIdx.x;
    const int wid = tid >> 6, lane = tid & 63;
    const int lr = lane & 15, ls = lane >> 4;
    const int wm = wid >> 2, wn = wid & 3;
    const size_t m0 = (size_t)by * 256, n0 = (size_t)bx * 192;

    const bf16_t* Ab = A + m0 * K;
    const bf16_t* Bb = BT + n0 * K;

    f32x4 acc[8][3];
#pragma unroll
    for (int m = 0; m < 8; m++)
#pragma unroll
        for (int n = 0; n < 3; n++) acc[m][n] = (f32x4){0.f, 0.f, 0.f, 0.f};
    bf16x8 bfr[3][2];
    bf16x8 afP[2][2], afQ[2][2];

#pragma unroll
    for (int p = 0; p < 4; p++) st512(As[0], Ab, K, p, tid);
#pragma unroll
    for (int p = 0; p < 3; p++) st512(Bs[0], Bb, K, p, tid);
    WAIT_VM0();
    BAR();

    const int nt = K >> 6;
#pragma unroll 1
    for (int i = 0; i < nt; ++i) {
        const int c = i & 1;
        const bf16_t* Ac = As[c];
        const bf16_t* Bc = Bs[c];
        if (i + 1 < nt) {
            const size_t ko = (size_t)(i + 1) * 64;
            bf16_t* Ad = As[c ^ 1];
            bf16_t* Bd = Bs[c ^ 1];
#pragma unroll
            for (int p = 0; p < 4; p++) st512(Ad, Ab + ko, K, p, tid);
#pragma unroll
            for (int p = 0; p < 3; p++) st512(Bd, Bb + ko, K, p, tid);
        }
        __builtin_amdgcn_sched_barrier(0);
        LDAQ(afP, Ac, 0);
        LDB3(Bc);
        LDAQ(afQ, Ac, 1);
        MMA3(0, afP);
        LDAQ(afP, Ac, 2);
        MMA3(1, afQ);
        LDAQ(afQ, Ac, 3);
        MMA3(2, afP);
        MMA3(3, afQ);
        WAIT_VM0();
        BAR();
    }

    float bv[3];
#pragma unroll
    for (int n = 0; n < 3; n++) bv[n] = bias[n0 + wn * 48 + n * 16 + lr];
#pragma unroll
    for (int mm = 0; mm < 8; mm++)
#pragma unroll
        for (int n = 0; n < 3; n++)
#pragma unroll
            for (int j = 0; j < 4; j++) {
                const size_t row = m0 + wm * 128 + mm * 16 + ls * 4 + j;
                const size_t col = n0 + wn * 48 + n * 16 + lr;
                C[row * N + col] = f2b(acc[mm][n][j] + bv[n]);
            }
}

// ---------------- 256x128 single-barrier GEMM (dense, 1 round) --------------
#define LDB2(bb) do {                                                          \
    _Pragma("unroll")                                                          \
    for (int n = 0; n < 2; n++)                                                \
        _Pragma("unroll")                                                      \
        for (int ks = 0; ks < 2; ks++) {                                       \
            const int r = wn * 32 + n * 16 + lr;                               \
            bfr[n][ks] = *(const bf16x8*)                                      \
                &(bb)[r * 64 + (((ks * 4 + ls) ^ (r & 7)) << 3)];              \
        }                                                                      \
} while (0)

#define MMA2(q, src) do {                                                      \
    __builtin_amdgcn_s_setprio(1);                                             \
    _Pragma("unroll")                                                          \
    for (int ks = 0; ks < 2; ks++)                                             \
        _Pragma("unroll")                                                      \
        for (int n = 0; n < 2; n++)                                            \
            _Pragma("unroll")                                                  \
            for (int m = 0; m < 2; m++)                                        \
                acc[(q) * 2 + m][n] =                                          \
                    mfma16(src[m][ks], bfr[n][ks], acc[(q) * 2 + m][n]);       \
    __builtin_amdgcn_s_setprio(0);                                             \
} while (0)

__global__ __launch_bounds__(512, 2) void gemm_dense(const bf16_t* __restrict__ A,
                                                     const bf16_t* __restrict__ BT,
                                                     const float* __restrict__ bias,
                                                     float* __restrict__ C,
                                                     int M, int N, int K) {
    __shared__ __align__(16) bf16_t As[2][256 * 64];
    __shared__ __align__(16) bf16_t Bs[2][128 * 64];

    const int nwg = (int)(gridDim.x * gridDim.y);
    const int id  = (int)(blockIdx.y * gridDim.x + blockIdx.x);
    const int wg  = (id & 7) * (nwg >> 3) + (id >> 3);
    const int bx  = wg % (int)gridDim.x, by = wg / (int)gridDim.x;

    const int tid = threadIdx.x;
    const int wid = tid >> 6, lane = tid & 63;
    const int lr = lane & 15, ls = lane >> 4;
    const int wm = wid >> 2, wn = wid & 3;
    const size_t m0 = (size_t)by * 256, n0 = (size_t)bx * 128;

    const bf16_t* Ab = A + m0 * K;
    const bf16_t* Bb = BT + n0 * K;

    f32x4 acc[8][2];
#pragma unroll
    for (int m = 0; m < 8; m++)
#pragma unroll
        for (int n = 0; n < 2; n++) acc[m][n] = (f32x4){0.f, 0.f, 0.f, 0.f};
    bf16x8 bfr[2][2];
    bf16x8 afP[2][2], afQ[2][2];

#pragma unroll
    for (int p = 0; p < 4; p++) st512(As[0], Ab, K, p, tid);
#pragma unroll
    for (int p = 0; p < 2; p++) st512(Bs[0], Bb, K, p, tid);
    WAIT_VM0();
    BAR();

    const int nt = K >> 6;
#pragma unroll 1
    for (int i = 0; i < nt; ++i) {
        const int c = i & 1;
        const bf16_t* Ac = As[c];
        const bf16_t* Bc = Bs[c];
        if (i + 1 < nt) {
            const size_t ko = (size_t)(i + 1) * 64;
            bf16_t* Ad = As[c ^ 1];
            bf16_t* Bd = Bs[c ^ 1];
#pragma unroll
            for (int p = 0; p < 4; p++) st512(Ad, Ab + ko, K, p, tid);
#pragma unroll
            for (int p = 0; p < 2; p++) st512(Bd, Bb + ko, K, p, tid);
        }
        __builtin_amdgcn_sched_barrier(0);
        LDAQ(afP, Ac, 0);
        LDB2(Bc);
        LDAQ(afQ, Ac, 1);
        MMA2(0, afP);
        LDAQ(afP, Ac, 2);
        MMA2(1, afQ);
        LDAQ(afQ, Ac, 3);
        MMA2(2, afP);
        MMA2(3, afQ);
        WAIT_VM0();
        BAR();
    }

    float bv[2];
#pragma unroll
    for (int n = 0; n < 2; n++) bv[n] = bias[n0 + wn * 32 + n * 16 + lr];
#pragma unroll
    for (int mm = 0; mm < 8; mm++)
#pragma unroll
        for (int n = 0; n < 2; n++)
#pragma unroll
            for (int j = 0; j < 4; j++) {
                const size_t row = m0 + wm * 128 + mm * 16 + ls * 4 + j;
                const size_t col = n0 + wn * 32 + n * 16 + lr;
                C[row * N + col] = acc[mm][n][j] + bv[n];
            }
}

// ---------------- RoPE on Q,K only (pow-2 indexing) ----------------
__global__ __launch_bounds__(256) void rope_qk(const bf16_t* __restrict__ qkv,
                                               const int* __restrict__ pos_ids,
                                               bf16_t* __restrict__ Qo,
                                               bf16_t* __restrict__ Ko) {
    const size_t gid = (size_t)blockIdx.x * 256 + threadIdx.x;
    const int d8 = (int)(gid & 15);
    const size_t t1 = gid >> 4;
    const int which = (int)(t1 & 1);
    const size_t t2 = t1 >> 1;
    const int nh = (int)(t2 & 15);
    const size_t bs = t2 >> 4;                  // b*S + s
    const int s = (int)(bs & (S_ - 1));
    const int b = (int)(bs >> 11);

    const bf16_t* src = qkv + bs * (3 * H_) + nh * 384 + which * 128 + d8 * 8;
    bf16x8 xv = *(const bf16x8*)src;
    const bf16_t* xu = (const bf16_t*)&xv;

    float xf[8];
#pragma unroll
    for (int i = 0; i < 8; i++) xf[i] = b2f(xu[i]);
    const int d0 = d8 * 8;
    if (d0 < 32) {
        const float pos = (float)pos_ids[bs];
        bf16x8 yv = *(const bf16x8*)(src + ((d0 < 16) ? 16 : -16));
        const bf16_t* yu = (const bf16_t*)&yv;
#pragma unroll
        for (int i = 0; i < 8; i++) {
            const int d = d0 + i;
            const float th = pos * exp2f(-(float)(d & 15) * L2B16);
            const float c = cosf(th), sn = sinf(th);
            const float rot = (d < 16) ? -b2f(yu[i]) : b2f(yu[i]);
            xf[i] = xf[i] * c + rot * sn;
        }
    }
    bf16_t ou[8];
#pragma unroll
    for (int i = 0; i < 8; i++) ou[i] = f2b(xf[i]);
    bf16_t* dst = ((which == 0) ? Qo : Ko) + ((size_t)(b * NH_ + nh) * S_ + s) * HS_ + d0;
    *(bf16x8*)dst = *(const bf16x8*)ou;
}

// ---------------- V transpose: (b,s,h,d) -> (bh, d, s), LDS-tiled ----------
__global__ __launch_bounds__(256) void vxpose(const bf16_t* __restrict__ qkv,
                                              bf16_t* __restrict__ Vt) {
    __shared__ bf16_t t[128][130];
    const int bh = (int)blockIdx.x >> 4;
    const int s0 = ((int)blockIdx.x & 15) << 7;
    const int b = bh >> 4, h = bh & 15;
    const int tid = threadIdx.x;

    const int dc = tid & 15, sl = tid >> 4;
    const bf16_t* src = qkv + ((size_t)b * S_ + s0) * (3 * H_) + h * 384 + 256 + dc * 8;
#pragma unroll
    for (int c = 0; c < 8; c++) {
        const int s = sl + c * 16;
        bf16x8 v = *(const bf16x8*)(src + (size_t)s * (3 * H_));
        *(bf16x8*)&t[s][dc * 8] = v;
    }
    __syncthreads();
    const int sc = tid & 15, dl = tid >> 4;
    bf16_t* dst = Vt + ((size_t)bh * HS_) * S_ + s0 + sc * 8;
#pragma unroll
    for (int c = 0; c < 8; c++) {
        const int d = dl + c * 16;
        bf16_t o[8];
#pragma unroll
        for (int i = 0; i < 8; i++) o[i] = t[sc * 8 + i][d];
        *(bf16x8*)(dst + (size_t)d * S_) = *(const bf16x8*)o;
    }
}

// ---------------- causal flash attention v4: QBLK=32/wave + pairing ---------
// Block = (bh, pair p): processes q-tile (15-p) then (p), 128 rows each ->
// exactly 36 KVBLK=64 steps per block (uniform; all 256 blocks co-resident).
// kf/vf shared across the two u-subtiles (2 MFMAs per LDS read); Ps reused
// u=0 -> u=1 with pf preloaded to registers (wave-local, in-order DS).
// XCD: block id = y*32+bh => XCD = bh&7 for all y; 4 bh's KV = 4MB = one L2.
__device__ __forceinline__ void attn_stage(bf16_t* Kd, bf16_t* Vd,
                                           const bf16_t* Kg, const bf16_t* Vg,
                                           int kv0, int wid, int lane) {
#pragma unroll
    for (int jj = 0; jj < 4; jj++) {
        const int c = (wid << 2) + jj;
        const int rk = (c << 2) + (lane >> 4);        // K row 0..63
        async16(Kd + c * 512,
                Kg + (size_t)(kv0 + rk) * HS_ + (((lane & 15) ^ (rk & 7)) << 3));
        const int rv = (c << 3) + (lane >> 3);        // V^T row 0..127
        async16(Vd + c * 512,
                Vg + (size_t)rv * S_ + kv0 + (((lane & 7) ^ (rv & 7)) << 3));
    }
}

__global__ __launch_bounds__(256) void attn_fwd(const bf16_t* __restrict__ Q,
                                                const bf16_t* __restrict__ Kv,
                                                const bf16_t* __restrict__ Vt,
                                                const float* __restrict__ amask,
                                                bf16_t* __restrict__ ctx) {
    __shared__ __align__(16) bf16_t Ks[2][64 * 128];
    __shared__ __align__(16) bf16_t Vs[2][128 * 64];
    __shared__ __align__(16) bf16_t Ps[4][16 * 72];

    const int bh = (int)blockIdx.x;               // XCD = bh & 7
    const int pr = (int)blockIdx.y;               // 0..7
    const int b = bh >> 4, h = bh & 15;
    const int tid = threadIdx.x, wid = tid >> 6, lane = tid & 63;
    const int lr = lane & 15, ls = lane >> 4;
    const float* am = amask + (size_t)b * S_;
    const bf16_t* Kg = Kv + (size_t)bh * S_ * HS_;
    const bf16_t* Vg = Vt + (size_t)bh * HS_ * S_;

#pragma unroll 1
    for (int half = 0; half < 2; ++half) {
        const int qt = half ? pr : (15 - pr);
        const int q0 = qt << 7;                   // 128-row q tile
        const int qb = q0 + wid * 32;             // wave's 32-row q base

        bf16x8 qf[2][4];
#pragma unroll
        for (int u = 0; u < 2; u++) {
            const bf16_t* qp = Q + ((size_t)bh * S_ + qb + u * 16 + lr) * HS_;
#pragma unroll
            for (int dk = 0; dk < 4; dk++)
                qf[u][dk] = *(const bf16x8*)(qp + dk * 32 + ls * 8);
        }

        float mrun[2] = { -3.0e38f, -3.0e38f }, lrun[2] = { 0.f, 0.f };
        f32x4 oacc[2][8];
#pragma unroll
        for (int u = 0; u < 2; u++)
#pragma unroll
            for (int dt = 0; dt < 8; dt++) oacc[u][dt] = (f32x4){0.f, 0.f, 0.f, 0.f};

        attn_stage(Ks[0], Vs[0], Kg, Vg, 0, wid, lane);
        const int nsteps = 2 * qt + 2;
#pragma unroll 1
        for (int step = 0; step < nsteps; ++step) {
            const int cur = step & 1;
            const int kv0 = step << 6;
            if (step + 1 < nsteps) {
                attn_stage(Ks[cur ^ 1], Vs[cur ^ 1], Kg, Vg, kv0 + 64, wid, lane);
                WAIT_VM8();
            } else {
                WAIT_VM0();
            }
            BAR();

            // QK^T, kf shared across u
            f32x4 sacc[2][4];
#pragma unroll
            for (int u = 0; u < 2; u++)
#pragma unroll
                for (int tt = 0; tt < 4; tt++) sacc[u][tt] = (f32x4){0.f, 0.f, 0.f, 0.f};
#pragma unroll
            for (int tt = 0; tt < 4; tt++)
#pragma unroll
                for (int dk = 0; dk < 4; dk++) {
                    const int row = tt * 16 + lr;
                    bf16x8 kf = *(const bf16x8*)
                        &Ks[cur][row * 128 + (((dk * 4 + ls) ^ (row & 7)) << 3)];
                    sacc[0][tt] = mfma16(kf, qf[0][dk], sacc[0][tt]);
                    sacc[1][tt] = mfma16(kf, qf[1][dk], sacc[1][tt]);
                }

            const bool diag = (step >= 2 * qt);
            bf16x8 pfr[2][2];
#pragma unroll
            for (int u = 0; u < 2; u++) {
                const int qrow = qb + u * 16 + lr;
                float sv[4][4];
                float rmax = -3.0e38f;
#pragma unroll
                for (int tt = 0; tt < 4; tt++) {
                    const float4 amv = *(const float4*)&am[kv0 + tt * 16 + ls * 4];
                    const float amj[4] = { amv.x, amv.y, amv.z, amv.w };
#pragma unroll
                    for (int j = 0; j < 4; j++) {
                        const int kvp = kv0 + tt * 16 + ls * 4 + j;
                        float v = sacc[u][tt][j] * NORM_ + amj[j];
                        if (diag && kvp > qrow) v = -3.0e38f;
                        sv[tt][j] = v;
                        rmax = fmaxf(rmax, v);
                    }
                }
                rmax = fmaxf(rmax, __shfl_xor(rmax, 16));
                rmax = fmaxf(rmax, __shfl_xor(rmax, 32));

                if (!__all((int)(rmax <= mrun[u]))) {
                    const float mnew = fmaxf(mrun[u], rmax);
                    const float sc = __expf(mrun[u] - mnew);
                    lrun[u] *= sc;
                    mrun[u] = mnew;
                    float scb[4];
#pragma unroll
                    for (int j = 0; j < 4; j++) scb[j] = __shfl(sc, ls * 4 + j);
#pragma unroll
                    for (int dt = 0; dt < 8; dt++)
#pragma unroll
                        for (int j = 0; j < 4; j++) oacc[u][dt][j] *= scb[j];
                }

                float psum = 0.f;
#pragma unroll
                for (int tt = 0; tt < 4; tt++) {
                    const float p0 = __expf(sv[tt][0] - mrun[u]);
                    const float p1 = __expf(sv[tt][1] - mrun[u]);
                    const float p2 = __expf(sv[tt][2] - mrun[u]);
                    const float p3 = __expf(sv[tt][3] - mrun[u]);
                    psum += (p0 + p1) + (p2 + p3);
                    const unsigned pk0 = (unsigned)f2b(p0) | ((unsigned)f2b(p1) << 16);
                    const unsigned pk1 = (unsigned)f2b(p2) | ((unsigned)f2b(p3) << 16);
                    *(unsigned*)&Ps[wid][lr * 72 + tt * 16 + ls * 4]     = pk0;
                    *(unsigned*)&Ps[wid][lr * 72 + tt * 16 + ls * 4 + 2] = pk1;
                }
                psum += __shfl_xor(psum, 16);
                psum += __shfl_xor(psum, 32);
                lrun[u] += psum;

                // preload this u's P-frags to registers, freeing Ps for next u
                pfr[u][0] = *(const bf16x8*)&Ps[wid][lr * 72 + ls * 8];
                pfr[u][1] = *(const bf16x8*)&Ps[wid][lr * 72 + 32 + ls * 8];
            }

            // PV, vf shared across u
#pragma unroll
            for (int dt = 0; dt < 8; dt++)
#pragma unroll
                for (int hh = 0; hh < 2; hh++) {
                    const int vrow = dt * 16 + lr;
                    bf16x8 vf = *(const bf16x8*)
                        &Vs[cur][vrow * 64 + (((hh * 4 + ls) ^ (vrow & 7)) << 3)];
                    oacc[0][dt] = mfma16(pfr[0][hh], vf, oacc[0][dt]);
                    oacc[1][dt] = mfma16(pfr[1][hh], vf, oacc[1][dt]);
                }
            BAR();
        }

#pragma unroll
        for (int u = 0; u < 2; u++) {
            const float inv = 1.0f / lrun[u];
            float invj[4];
#pragma unroll
            for (int j = 0; j < 4; j++) invj[j] = __shfl(inv, ls * 4 + j);
#pragma unroll
            for (int j = 0; j < 4; j++) {
                bf16_t* dst = ctx + ((size_t)b * S_ + qb + u * 16 + ls * 4 + j) * H_ + h * HS_;
#pragma unroll
                for (int dt = 0; dt < 8; dt++)
                    dst[dt * 16 + lr] = f2b(oacc[u][dt][j] * invj[j]);
            }
        }
    }
}

extern "C" void kernel_launch(void* const* d_in, const int* in_sizes, int n_in,
                              void* d_out, int out_size, void* d_ws, size_t ws_size,
                              hipStream_t stream) {
    const float* hs   = (const float*)d_in[0];
    const float* am   = (const float*)d_in[1];
    const int*   pos  = (const int*)d_in[2];
    const float* Wqkv = (const float*)d_in[3];
    const float* bqkv = (const float*)d_in[4];
    const float* Wd   = (const float*)d_in[5];
    const float* bd   = (const float*)d_in[6];
    float* out = (float*)d_out;
    char*  ws  = (char*)d_ws;

    const size_t MB = 1024 * 1024;
    bf16_t* X    = (bf16_t*)(ws);              // 16 MB (reused as ctx)
    bf16_t* WqT  = (bf16_t*)(ws + 16 * MB);    // 24 MB
    bf16_t* WdT  = (bf16_t*)(ws + 40 * MB);    // 8 MB
    bf16_t* QKVb = (bf16_t*)(ws + 48 * MB);    // 48 MB
    bf16_t* Qb   = (bf16_t*)(ws + 96 * MB);    // 16 MB
    bf16_t* Kb   = (bf16_t*)(ws + 112 * MB);   // 16 MB
    bf16_t* Vtb  = (bf16_t*)(ws + 128 * MB);   // 16 MB
    bf16_t* ctx  = X;

    cvt_bf16<<<4096, 256, 0, stream>>>(hs, X);
    transpose_cvt<<<dim3(6144 / 32, 2048 / 32), 256, 0, stream>>>(Wqkv, WqT, 2048, 6144);
    transpose_cvt<<<dim3(2048 / 32, 2048 / 32), 256, 0, stream>>>(Wd, WdT, 2048, 2048);
    gemm_qkv<<<dim3(32, 16), 512, 0, stream>>>(X, WqT, bqkv, QKVb, 4096, 6144, 2048);
    rope_qk<<<8192, 256, 0, stream>>>(QKVb, pos, Qb, Kb);
    vxpose<<<512, 256, 0, stream>>>(QKVb, Vtb);
    attn_fwd<<<dim3(32, 8), 256, 0, stream>>>(Qb, Kb, Vtb, am, ctx);
    gemm_dense<<<dim3(16, 16), 512, 0, stream>>>(ctx, WdT, bd, out, 4096, 2048, 2048);
}